// Round 2
// baseline (952.188 us; speedup 1.0000x reference)
//
#include <hip/hip_runtime.h>
#include <cstdint>

typedef unsigned short u16;
typedef unsigned long long u64;
typedef __attribute__((ext_vector_type(8))) short short8;
typedef __attribute__((ext_vector_type(4))) float floatx4;

#define DEV __device__ __forceinline__

// async global->LDS, 16B per lane; LDS dest must be wave-uniform base + lane*16
#define GLD16(gp, lp)                                                          \
  __builtin_amdgcn_global_load_lds(                                            \
      (const __attribute__((address_space(1))) void*)(gp),                     \
      (__attribute__((address_space(3))) void*)(lp), 16, 0, 0)

DEV u16 f2bf(float f) {  // round-to-nearest-even bf16
  union { float f; uint32_t u; } x; x.f = f;
  uint32_t r = x.u + 0x7fffu + ((x.u >> 16) & 1u);
  return (u16)(r >> 16);
}

// Problem constants: B=2, L=2048, D=1024, H=16, DK=64.

// ---------------------------------------------------------------- fp32->bf16
__global__ __launch_bounds__(256) void cvt_bf16(
    const float* __restrict__ src, u16* __restrict__ dst) {
  int i = (blockIdx.x * 256 + threadIdx.x) * 4;   // n = 4M, grid covers exactly
  float4 v = *(const float4*)(src + i);
  ushort4 o;
  o.x = f2bf(v.x); o.y = f2bf(v.y); o.z = f2bf(v.z); o.w = f2bf(v.w);
  *(ushort4*)(dst + i) = o;
}

// ---------------------------------------------------------------- mask pack
// one 64-bit word per 64 mask elements via __ballot; mw[c] covers flat [c*64, c*64+64)
__global__ __launch_bounds__(256) void pack_mask(
    const int* __restrict__ mask, u64* __restrict__ mw) {
  const int lane = threadIdx.x & 63;
  int gw = (blockIdx.x * 256 + threadIdx.x) >> 6;
  const int nwaves = (gridDim.x * 256) >> 6;
  const int total = (2 * 2048 * 2048) / 64;       // 131072 words
  for (int c = gw; c < total; c += nwaves) {
    int v = mask[(size_t)c * 64 + lane];
    u64 b = __ballot(v != 0);
    if (lane == 0) mw[c] = b;
  }
}

// ---------------------------------------------------------------- transpose
// Wt[n][k] = W[k][n] (fp32 in, bf16 out), 1024x1024; z picks which weight
__global__ __launch_bounds__(256) void transpose_w(
    const float* __restrict__ s0, const float* __restrict__ s1,
    const float* __restrict__ s2, const float* __restrict__ s3,
    u16* __restrict__ d0, u16* __restrict__ d1,
    u16* __restrict__ d2, u16* __restrict__ d3) {
  const float* S; u16* D;
  switch (blockIdx.z) {
    case 0: S = s0; D = d0; break;
    case 1: S = s1; D = d1; break;
    case 2: S = s2; D = d2; break;
    default: S = s3; D = d3; break;
  }
  __shared__ u16 t[64][68];
  const int tid = threadIdx.x;
  const int r0 = blockIdx.y * 64, c0 = blockIdx.x * 64;
#pragma unroll
  for (int i = 0; i < 4; ++i) {
    int idx = i * 256 + tid;
    int r = idx >> 4, c = (idx & 15) * 4;
    float4 v = *(const float4*)(S + (size_t)(r0 + r) * 1024 + c0 + c);
    t[r][c] = f2bf(v.x); t[r][c + 1] = f2bf(v.y);
    t[r][c + 2] = f2bf(v.z); t[r][c + 3] = f2bf(v.w);
  }
  __syncthreads();
#pragma unroll
  for (int i = 0; i < 4; ++i) {
    int idx = i * 256 + tid;
    int r = idx >> 4, c = (idx & 15) * 4;
    ushort4 v;
    v.x = t[c][r]; v.y = t[c + 1][r]; v.z = t[c + 2][r]; v.w = t[c + 3][r];
    *(ushort4*)(D + (size_t)(c0 + r) * 1024 + r0 + c) = v;
  }
}

// ---------------------------------------------------------------- GEMM
// C[4096x1024] = X[4096x1024](bf16) @ Wt^T (Wt is [n][k] bf16) + bias(fp32)
// mode 0: write bf16 [b,h,l,dk]   (Q/K projections)
// mode 1: write bf16 [b,h,dk,l]   (V projection, transposed for PV B-operand)
// mode 2: write fp32 row-major [m][n]  (final output)
__global__ __launch_bounds__(256) void gemm128(
    const u16* __restrict__ X, const u16* __restrict__ Wt,
    const float* __restrict__ bias, u16* __restrict__ outb,
    float* __restrict__ outf, int mode) {
  __shared__ __align__(16) u16 As[128 * 32];
  __shared__ __align__(16) u16 Bs[128 * 32];
  const int tid = threadIdx.x;
  const int wave = tid >> 6, lane = tid & 63;
  const int quad = lane >> 4, l16 = lane & 15;
  const int wm = (wave >> 1) * 64, wn = (wave & 1) * 64;
  const int m0 = blockIdx.x * 128, n0 = blockIdx.y * 128;

  floatx4 acc[4][4];
#pragma unroll
  for (int i = 0; i < 4; ++i)
#pragma unroll
    for (int j = 0; j < 4; ++j) acc[i][j] = (floatx4){0.f, 0.f, 0.f, 0.f};

  for (int k0 = 0; k0 < 1024; k0 += 32) {
#pragma unroll
    for (int r = 0; r < 2; ++r) {
      int c = r * 256 + tid;
      int row = c >> 2, off = (c & 3) * 8;
      GLD16(X + (size_t)(m0 + row) * 1024 + k0 + off, As + c * 8);
      GLD16(Wt + (size_t)(n0 + row) * 1024 + k0 + off, Bs + c * 8);
    }
    __syncthreads();
    short8 a[4], b[4];
#pragma unroll
    for (int i = 0; i < 4; ++i)
      a[i] = *(const short8*)(As + (wm + i * 16 + l16) * 32 + quad * 8);
#pragma unroll
    for (int i = 0; i < 4; ++i)
      b[i] = *(const short8*)(Bs + (wn + i * 16 + l16) * 32 + quad * 8);
#pragma unroll
    for (int mi = 0; mi < 4; ++mi)
#pragma unroll
      for (int ni = 0; ni < 4; ++ni)
        acc[mi][ni] = __builtin_amdgcn_mfma_f32_16x16x32_bf16(
            a[mi], b[ni], acc[mi][ni], 0, 0, 0);
    __syncthreads();
  }

#pragma unroll
  for (int mi = 0; mi < 4; ++mi) {
#pragma unroll
    for (int ni = 0; ni < 4; ++ni) {
      const int gn = n0 + wn + ni * 16 + l16;
      const float bv = bias[gn];
#pragma unroll
      for (int reg = 0; reg < 4; ++reg) {
        const int gm = m0 + wm + mi * 16 + quad * 4 + reg;
        const float v = acc[mi][ni][reg] + bv;
        if (mode == 2) {
          outf[(size_t)gm * 1024 + gn] = v;
        } else {
          int bb = gm >> 11, l = gm & 2047, hh = gn >> 6, dk = gn & 63;
          size_t addr = (mode == 0)
              ? (((size_t)(bb * 16 + hh) * 2048 + l) * 64 + dk)
              : (((size_t)(bb * 16 + hh) * 64 + dk) * 2048 + l);
          outb[addr] = f2bf(v);
        }
      }
    }
  }
}

// ---------------------------------------------------------------- rowsum
// one workgroup = (b, h, 64 q-rows); waves split the 128-key tile (32 keys ea)
__global__ __launch_bounds__(256) void rowsum_k(
    const u16* __restrict__ qh, const u16* __restrict__ kh,
    const u64* __restrict__ mw, float* __restrict__ rowinv) {
  const int tid = threadIdx.x;
  const int wave = tid >> 6, lane = tid & 63;
  const int quad = lane >> 4, l16 = lane & 15;
  const int q0 = blockIdx.x * 64, h = blockIdx.y, b = blockIdx.z;
  const int bh = b * 16 + h;

  __shared__ __align__(16) u16 Qs[64 * 72];    // pad 72: 2-way banks (free)
  __shared__ __align__(16) u16 Ks[128 * 72];
  __shared__ float red[4][64];

  const u16* qbase = qh + ((size_t)bh * 2048 + q0) * 64;
  const u16* kbase = kh + (size_t)bh * 2048 * 64;
  const u64* mwrow = mw + ((size_t)b * 2048 + q0) * 32;

#pragma unroll
  for (int r = 0; r < 2; ++r) {
    int c = r * 256 + tid;
    int row = c >> 3, off = (c & 7) * 8;
    uint4 v = *(const uint4*)(qbase + (size_t)c * 8);
    *(uint4*)(Qs + row * 72 + off) = v;
  }

  float rs[4][4];
#pragma unroll
  for (int i = 0; i < 4; ++i)
#pragma unroll
    for (int j = 0; j < 4; ++j) rs[i][j] = 0.f;

  for (int kt = 0; kt < 16; ++kt) {
#pragma unroll
    for (int r = 0; r < 4; ++r) {
      int c = r * 256 + tid;
      int row = c >> 3, off = (c & 7) * 8;
      uint4 v = *(const uint4*)(kbase + (size_t)kt * 8192 + c * 8);
      *(uint4*)(Ks + row * 72 + off) = v;
    }
    __syncthreads();

    floatx4 s[4][2];
#pragma unroll
    for (int i = 0; i < 4; ++i) {
      s[i][0] = (floatx4){0.f, 0.f, 0.f, 0.f};
      s[i][1] = (floatx4){0.f, 0.f, 0.f, 0.f};
    }
#pragma unroll
    for (int kk = 0; kk < 64; kk += 32) {
      short8 a[4], bb[2];
#pragma unroll
      for (int i = 0; i < 4; ++i)
        a[i] = *(const short8*)(Qs + (i * 16 + l16) * 72 + kk + quad * 8);
#pragma unroll
      for (int j = 0; j < 2; ++j)
        bb[j] = *(const short8*)(Ks + (wave * 32 + j * 16 + l16) * 72 + kk + quad * 8);
#pragma unroll
      for (int mi = 0; mi < 4; ++mi)
#pragma unroll
        for (int ni = 0; ni < 2; ++ni)
          s[mi][ni] = __builtin_amdgcn_mfma_f32_16x16x32_bf16(
              a[mi], bb[ni], s[mi][ni], 0, 0, 0);
    }
#pragma unroll
    for (int mi = 0; mi < 4; ++mi)
#pragma unroll
      for (int reg = 0; reg < 4; ++reg) {
        int row = mi * 16 + quad * 4 + reg;
        u64 w = mwrow[row * 32 + kt * 2 + (wave >> 1)];
#pragma unroll
        for (int ni = 0; ni < 2; ++ni) {
          int bit = (wave & 1) * 32 + ni * 16 + l16;
          float sv = s[mi][ni][reg] * (1.0f / 1024.0f);
          rs[mi][reg] += ((w >> bit) & 1) ? __expf(sv) : 0.f;
        }
      }
    __syncthreads();
  }

#pragma unroll
  for (int mi = 0; mi < 4; ++mi)
#pragma unroll
    for (int reg = 0; reg < 4; ++reg) {
      float v = rs[mi][reg];
      v += __shfl_xor(v, 1, 64);
      v += __shfl_xor(v, 2, 64);
      v += __shfl_xor(v, 4, 64);
      v += __shfl_xor(v, 8, 64);
      rs[mi][reg] = v;
    }
  if (l16 == 0) {
#pragma unroll
    for (int mi = 0; mi < 4; ++mi)
#pragma unroll
      for (int reg = 0; reg < 4; ++reg)
        red[wave][mi * 16 + quad * 4 + reg] = rs[mi][reg];
  }
  __syncthreads();
  if (tid < 64) {
    float sum = red[0][tid] + red[1][tid] + red[2][tid] + red[3][tid];
    rowinv[(size_t)bh * 2048 + q0 + tid] = (sum > 0.f) ? (1.0f / sum) : -1.0f;
  }
}

// ---------------------------------------------------------------- attention
__global__ __launch_bounds__(256) void attn_k(
    const u16* __restrict__ qh, const u16* __restrict__ kh,
    const u16* __restrict__ vt, const u64* __restrict__ mw,
    const float* __restrict__ rowinv, float* __restrict__ attn_out,
    u16* __restrict__ ctx) {
  const int tid = threadIdx.x;
  const int wave = tid >> 6, lane = tid & 63;
  const int quad = lane >> 4, l16 = lane & 15;
  const int q0 = blockIdx.x * 64, h = blockIdx.y, b = blockIdx.z;
  const int bh = b * 16 + h;

  __shared__ __align__(16) u16 Qs[64 * 72];
  __shared__ __align__(16) u16 Ks[128 * 72];
  __shared__ __align__(16) u16 Vs[64 * 136];   // [dk][key], pad 136
  __shared__ __align__(16) u16 Ps[64 * 136];   // [row][key], pad 136

  const u16* qbase = qh + ((size_t)bh * 2048 + q0) * 64;
  const u16* kbase = kh + (size_t)bh * 2048 * 64;
  const u16* vbase = vt + (size_t)bh * 64 * 2048;
  const u64* mwrow = mw + ((size_t)b * 2048 + q0) * 32;
  float* abase = attn_out + ((size_t)(h * 2 + b) * 2048 + q0) * 2048;

#pragma unroll
  for (int r = 0; r < 2; ++r) {
    int c = r * 256 + tid;
    int row = c >> 3, off = (c & 7) * 8;
    uint4 v = *(const uint4*)(qbase + (size_t)c * 8);
    *(uint4*)(Qs + row * 72 + off) = v;
  }

  float inv[4][4];
#pragma unroll
  for (int mi = 0; mi < 4; ++mi)
#pragma unroll
    for (int reg = 0; reg < 4; ++reg)
      inv[mi][reg] = rowinv[(size_t)bh * 2048 + q0 + mi * 16 + quad * 4 + reg];

  floatx4 cacc[4];
#pragma unroll
  for (int i = 0; i < 4; ++i) cacc[i] = (floatx4){0.f, 0.f, 0.f, 0.f};

  for (int kt = 0; kt < 16; ++kt) {
    // stage K tile [128][64] and V^T tile [64][128] (reg->LDS, padded)
#pragma unroll
    for (int r = 0; r < 4; ++r) {
      int c = r * 256 + tid;
      int row = c >> 3, off = (c & 7) * 8;
      uint4 v = *(const uint4*)(kbase + (size_t)kt * 8192 + c * 8);
      *(uint4*)(Ks + row * 72 + off) = v;
      int dk = c >> 4, ko = (c & 15) * 8;
      uint4 w = *(const uint4*)(vbase + (size_t)dk * 2048 + kt * 128 + ko);
      *(uint4*)(Vs + dk * 136 + ko) = w;
    }
    __syncthreads();

    // S = Q K^T
    floatx4 s[4][2];
#pragma unroll
    for (int i = 0; i < 4; ++i) {
      s[i][0] = (floatx4){0.f, 0.f, 0.f, 0.f};
      s[i][1] = (floatx4){0.f, 0.f, 0.f, 0.f};
    }
#pragma unroll
    for (int kk = 0; kk < 64; kk += 32) {
      short8 a[4], bb[2];
#pragma unroll
      for (int i = 0; i < 4; ++i)
        a[i] = *(const short8*)(Qs + (i * 16 + l16) * 72 + kk + quad * 8);
#pragma unroll
      for (int j = 0; j < 2; ++j)
        bb[j] = *(const short8*)(Ks + (wave * 32 + j * 16 + l16) * 72 + kk + quad * 8);
#pragma unroll
      for (int mi = 0; mi < 4; ++mi)
#pragma unroll
        for (int ni = 0; ni < 2; ++ni)
          s[mi][ni] = __builtin_amdgcn_mfma_f32_16x16x32_bf16(
              a[mi], bb[ni], s[mi][ni], 0, 0, 0);
    }

    // p = exp(s)/Z (masked): write fp32 attn + stage bf16 P
#pragma unroll
    for (int mi = 0; mi < 4; ++mi)
#pragma unroll
      for (int reg = 0; reg < 4; ++reg) {
        int row = mi * 16 + quad * 4 + reg;
        u64 w = mwrow[row * 32 + kt * 2 + (wave >> 1)];
        float iv = inv[mi][reg];
#pragma unroll
        for (int ni = 0; ni < 2; ++ni) {
          int keyl = wave * 32 + ni * 16 + l16;
          int key = kt * 128 + keyl;
          int bit = (wave & 1) * 32 + ni * 16 + l16;
          float sv = s[mi][ni][reg] * (1.0f / 1024.0f);
          float p = (iv < 0.f) ? (1.0f / 2048.0f)
                               : (((w >> bit) & 1) ? __expf(sv) * iv : 0.f);
          abase[(size_t)row * 2048 + key] = p;
          Ps[row * 136 + keyl] = f2bf(p);
        }
      }
    __syncthreads();

    // ctx += P @ V ; wave owns dk slice [wave*16, wave*16+16)
#pragma unroll
    for (int ks = 0; ks < 4; ++ks) {
      short8 a[4];
#pragma unroll
      for (int mi = 0; mi < 4; ++mi)
        a[mi] = *(const short8*)(Ps + (mi * 16 + l16) * 136 + ks * 32 + quad * 8);
      short8 bb = *(const short8*)(Vs + (wave * 16 + l16) * 136 + ks * 32 + quad * 8);
#pragma unroll
      for (int mi = 0; mi < 4; ++mi)
        cacc[mi] = __builtin_amdgcn_mfma_f32_16x16x32_bf16(a[mi], bb, cacc[mi], 0, 0, 0);
    }
    __syncthreads();
  }

  // write ctx [b][l][h*64+dk] (bf16 ws)
#pragma unroll
  for (int mi = 0; mi < 4; ++mi)
#pragma unroll
    for (int reg = 0; reg < 4; ++reg) {
      int row = q0 + mi * 16 + quad * 4 + reg;
      int col = h * 64 + wave * 16 + l16;
      ctx[(size_t)(b * 2048 + row) * 1024 + col] = f2bf(cacc[mi][reg]);
    }
}

// ---------------------------------------------------------------- launch
extern "C" void kernel_launch(void* const* d_in, const int* in_sizes, int n_in,
                              void* d_out, int out_size, void* d_ws, size_t ws_size,
                              hipStream_t stream) {
  const float* q    = (const float*)d_in[0];
  const float* k    = (const float*)d_in[1];
  const float* v    = (const float*)d_in[2];
  const int*   mask = (const int*)d_in[3];
  const float* Wq   = (const float*)d_in[4];
  const float* bq   = (const float*)d_in[5];
  const float* Wk   = (const float*)d_in[6];
  const float* bk   = (const float*)d_in[7];
  const float* Wv   = (const float*)d_in[8];
  const float* bv   = (const float*)d_in[9];
  const float* Wo   = (const float*)d_in[10];
  const float* bo   = (const float*)d_in[11];

  float* out  = (float*)d_out;                    // [4096][1024] fp32
  float* attn = out + (size_t)4096 * 1024;        // [32][2048][2048] fp32

  const size_t M = 1u << 20;
  u16* wtq = (u16*)d_ws;                          // 4 x 1M elems bf16 (W^T)
  u16* wtk = wtq + M;
  u16* wtv = wtk + M;
  u16* wto = wtv + M;
  u16* xb  = wto + M;                             // bf16 input buf (reused) 4M
  u16* qh  = xb + 4 * M;                          // [b,h,l,dk]  4M
  u16* kh  = qh + 4 * M;
  u16* vt  = kh + 4 * M;                          // [b,h,dk,l]
  u16* ctx = xb;                                  // reuse xb after V gemm
  float* rinv = (float*)(vt + 4 * M);             // [b,h,l] 64K floats
  u64* mw = (u64*)(rinv + 64 * 1024);             // 131072 words (1 MB)

  pack_mask<<<dim3(512), 256, 0, stream>>>(mask, mw);
  transpose_w<<<dim3(16, 16, 4), 256, 0, stream>>>(Wq, Wk, Wv, Wo, wtq, wtk, wtv, wto);

  cvt_bf16<<<dim3(4096), 256, 0, stream>>>(q, xb);
  gemm128<<<dim3(32, 8), 256, 0, stream>>>(xb, wtq, bq, qh, nullptr, 0);
  cvt_bf16<<<dim3(4096), 256, 0, stream>>>(k, xb);
  gemm128<<<dim3(32, 8), 256, 0, stream>>>(xb, wtk, bk, kh, nullptr, 0);
  cvt_bf16<<<dim3(4096), 256, 0, stream>>>(v, xb);
  gemm128<<<dim3(32, 8), 256, 0, stream>>>(xb, wtv, bv, vt, nullptr, 1);

  rowsum_k<<<dim3(32, 16, 2), 256, 0, stream>>>(qh, kh, mw, rinv);
  attn_k<<<dim3(32, 16, 2), 256, 0, stream>>>(qh, kh, vt, mw, rinv, attn, ctx);
  gemm128<<<dim3(32, 8), 256, 0, stream>>>(ctx, wto, bo, nullptr, out, 2);
}